// Round 11
// baseline (299.714 us; speedup 1.0000x reference)
//
#include <hip/hip_runtime.h>
#include <hip/hip_bf16.h>

#define B_SZ 8192
#define S_DIM 512
#define H_DIM 1024
#define E_DIM 256
#define A_DIM 32

typedef __attribute__((ext_vector_type(4))) float f32x4;
typedef __attribute__((ext_vector_type(8))) __bf16 bf16x8;
typedef __attribute__((ext_vector_type(4))) int i32x4;
typedef __attribute__((ext_vector_type(8))) int i32x8;

using as1_void = __attribute__((address_space(1))) void;
using as3_void = __attribute__((address_space(3))) void;

#define WAITV(N) asm volatile("s_waitcnt vmcnt(" #N ")" ::: "memory")

__device__ __forceinline__ unsigned short f2bfu(float f) {
  unsigned u = __builtin_bit_cast(unsigned, f);
  unsigned r = (u + 0x7FFFu + ((u >> 16) & 1u)) >> 16;
  return (unsigned short)r;
}
__device__ __forceinline__ float bf2f(unsigned short x) {
  unsigned u = ((unsigned)x) << 16;
  return __builtin_bit_cast(float, u);
}
// f32 -> OCP e4m3 via HW packed convert (byte 0)
__device__ __forceinline__ unsigned char f2fp8(float f) {
  return (unsigned char)(__builtin_amdgcn_cvt_pk_fp8_f32(f, f, 0, false) & 0xFF);
}

// 16-lane xor-butterfly sum via DPP (VALU pipe, no LDS traffic).
__device__ __forceinline__ float row16_sum(float s) {
  float t;
  t = __builtin_bit_cast(float, __builtin_amdgcn_update_dpp(
          0, __builtin_bit_cast(int, s), 0xB1, 0xF, 0xF, true));
  s += t;
  t = __builtin_bit_cast(float, __builtin_amdgcn_update_dpp(
          0, __builtin_bit_cast(int, s), 0x4E, 0xF, 0xF, true));
  s += t;
  t = __builtin_bit_cast(float, __builtin_amdgcn_update_dpp(
          0, __builtin_bit_cast(int, s), 0x141, 0xF, 0xF, true));
  s += t;
  t = __builtin_bit_cast(float, __builtin_amdgcn_update_dpp(
          0, __builtin_bit_cast(int, s), 0x140, 0xF, 0xF, true));
  s += t;
  return s;
}

// ---------------- single mega prep kernel ------------------------------------------------
#define PREP_BLOCKS 13866
__global__ void prep_kernel(const float* __restrict__ states, const float* __restrict__ hw1_w1,
                            const float* __restrict__ hwf_w1, const float* __restrict__ hb1_w,
                            const float* __restrict__ v_w1, const float* __restrict__ hw1_w2,
                            const float* __restrict__ hwf_w2, const float* __restrict__ hw1_b1,
                            const float* __restrict__ hwf_b1, const float* __restrict__ hb1_b,
                            const float* __restrict__ v_b1, const float* __restrict__ hw1_b2,
                            unsigned short* __restrict__ st_bf, unsigned short* __restrict__ wcat,
                            unsigned char* __restrict__ w8T, unsigned short* __restrict__ wf2T,
                            float* __restrict__ bcatp, float* __restrict__ bias_p) {
  __shared__ float t[32][33];
  const int tid = threadIdx.x;
  int b = blockIdx.x;
  if (b < 4096) {  // conv
    int idx = b * 1024 + tid * 4;
    const float4 v = *(const float4*)(states + idx);
    ushort4 o;
    o.x = f2bfu(v.x); o.y = f2bfu(v.y); o.z = f2bfu(v.z); o.w = f2bfu(v.w);
    *(ushort4*)(st_bf + idx) = o;
    return;
  }
  b -= 4096;
  if (b >= 9728) {  // bcat / bperm
    b -= 9728;
    if (b < 10) {
      int i = b * 256 + tid;
      if (i < 2560) {
        float v;
        if (i < 1024) v = hw1_b1[i];
        else if (i < 2048) v = hwf_b1[i - 1024];
        else if (i < 2304) v = hb1_b[i - 2048];
        else v = v_b1[i - 2304];
        bcatp[i] = v;
      }
    } else {
      int n = (b - 10) * 256 + tid;
      bias_p[n] = hw1_b2[((n & 31) << 8) + (n >> 5)];
    }
    return;
  }
  // transpose jobs
  const float* src;
  unsigned short* dst;
  int R, C, tile;
  bool perm = false;
  if (b < 512) { src = hw1_w1; dst = wcat; R = 512; C = 1024; tile = b; }
  else if (b < 1024) { src = hwf_w1; dst = wcat + (size_t)1024 * 512; R = 512; C = 1024; tile = b - 512; }
  else if (b < 1152) { src = hb1_w; dst = wcat + (size_t)2048 * 512; R = 512; C = 256; tile = b - 1024; }
  else if (b < 1280) { src = v_w1; dst = wcat + (size_t)2304 * 512; R = 512; C = 256; tile = b - 1152; }
  else if (b < 9472) { src = hw1_w2; dst = nullptr; R = 1024; C = 8192; tile = b - 1280; perm = true; }
  else { src = hwf_w2; dst = wf2T; R = 1024; C = 256; tile = b - 9472; }
  const int tpc = C >> 5;
  const int c0 = (tile % tpc) * 32, r0 = (tile / tpc) * 32;
  const int tx = tid & 31, ty = tid >> 5;
#pragma unroll
  for (int i = 0; i < 4; ++i) {
    int r = r0 + ty + i * 8;
    t[ty + i * 8][tx] = src[(size_t)r * C + c0 + tx];
  }
  __syncthreads();
#pragma unroll
  for (int i = 0; i < 4; ++i) {
    int c = c0 + ty + i * 8;
    if (perm) {
      size_t co = (size_t)(((c & 255) << 5) + (c >> 8));
      w8T[co * 1024 + r0 + tx] = f2fp8(t[tx][ty + i * 8]);
    } else {
      dst[(size_t)c * R + r0 + tx] = f2bfu(t[tx][ty + i * 8]);
    }
  }
}

// ---------------- 128x128 2-phase GEMM (m97 structure) -----------------------------------
// ACT==2: abs -> bf16. ACT==3 (S-GEMM): relu except cols [2048,2304); cols<1024 -> fp8 a8,
// else bf16 Cp.
template <int ACT>
__global__ void gemm_bt(const unsigned short* __restrict__ A, int Astr,
                        const unsigned short* __restrict__ BT,
                        const float* __restrict__ bias, void* __restrict__ Cp,
                        unsigned char* __restrict__ a8, int M, int N, int K) {
  __shared__ unsigned short As[128 * 64];
  __shared__ unsigned short Bs[128 * 64];
  const int tid = threadIdx.x;
  const int w = tid >> 6, l = tid & 63;
  const int wr = w >> 1, wc = w & 1;
  const int row0 = blockIdx.y * 128, col0 = blockIdx.x * 128;
  f32x4 acc[4][4] = {};
  for (int k0 = 0; k0 < K; k0 += 64) {
    __syncthreads();
#pragma unroll
    for (int i = 0; i < 4; ++i) {
      int cbase = i * 256 + w * 64;
      int c = cbase + l;
      int r = c >> 3, kc = c & 7;
      const unsigned short* src = A + (size_t)(row0 + r) * Astr + (k0 + kc * 8);
      __builtin_amdgcn_global_load_lds((const as1_void*)src, (as3_void*)&As[cbase * 8], 16, 0, 0);
    }
#pragma unroll
    for (int i = 0; i < 4; ++i) {
      int cbase = i * 256 + w * 64;
      int c = cbase + l;
      int r = c >> 3, kc = c & 7;
      const unsigned short* src = BT + (size_t)(col0 + r) * K + (k0 + kc * 8);
      __builtin_amdgcn_global_load_lds((const as1_void*)src, (as3_void*)&Bs[cbase * 8], 16, 0, 0);
    }
    __syncthreads();
#pragma unroll
    for (int kk = 0; kk < 2; ++kk) {
      bf16x8 af[4], bfr[4];
#pragma unroll
      for (int i = 0; i < 4; ++i)
        af[i] = *(const bf16x8*)&As[(wr * 64 + i * 16 + (l & 15)) * 64 + kk * 32 + (l >> 4) * 8];
#pragma unroll
      for (int j = 0; j < 4; ++j)
        bfr[j] = *(const bf16x8*)&Bs[(wc * 64 + j * 16 + (l & 15)) * 64 + kk * 32 + (l >> 4) * 8];
#pragma unroll
      for (int i = 0; i < 4; ++i)
#pragma unroll
        for (int j = 0; j < 4; ++j)
          acc[i][j] = __builtin_amdgcn_mfma_f32_16x16x32_bf16(af[i], bfr[j], acc[i][j], 0, 0, 0);
    }
  }
#pragma unroll
  for (int i = 0; i < 4; ++i)
#pragma unroll
    for (int j = 0; j < 4; ++j)
#pragma unroll
      for (int t = 0; t < 4; ++t) {
        int r = row0 + wr * 64 + i * 16 + (l >> 4) * 4 + t;
        int c = col0 + wc * 64 + j * 16 + (l & 15);
        float v = acc[i][j][t] + bias[c];
        if (ACT == 2) {
          v = fabsf(v);
          ((unsigned short*)Cp)[(size_t)r * N + c] = f2bfu(v);
        } else {  // ACT == 3
          if (!(c >= 2048 && c < 2304)) v = fmaxf(v, 0.0f);
          if (c < 1024)
            a8[(size_t)r * 1024 + c] = f2fp8(v);
          else
            ((unsigned short*)Cp)[(size_t)r * N + c] = f2bfu(v);
        }
      }
}

// ---------------- 256x256 MX-fp8 K=128 pipelined GEMM + fused agent contraction ----------
// r7-proven snake schedule, SINGLE bfr set (no double-B-hold — r10's +16 VGPR hold blew the
// 256-reg/wave budget at 2 waves/SIMD and spilled ~223 MB to scratch):
//   p0 q(0,0)[lda0,ldb0]; p1 q(0,1)[ldb1]; p2 q(1,1)[lda1]; p3 q(1,0)[ldb0 re-read].
// Stage slots into nbuf: p0:A0, p1:B0, p2:B1, p3:A1; WAITV(4) at p0/p1/p3 (p2 none).
// FIFO invariant at p0 entry: [B1(t)x2, A1(t)x2] = 4 outstanding. Peel: WAITV(2)/WAITV(0).
// fp8 e4m3 both operands, unit e8m0 scales (127) -> plain fp8 GEMM at 2x bf16 rate.
// Fragment regs: af 32 + bfr 16 = 48 (same as proven bf16 r7/r9) + acc 128 -> ~248, no spill.
__global__ __launch_bounds__(512, 2) void gemm256_f8(
    const unsigned char* __restrict__ A, const unsigned char* __restrict__ BT,
    const float* __restrict__ bias, const float* __restrict__ qs,
    float* __restrict__ hid, int M, int N, int K) {
  __shared__ __align__(16) char smem[131072];  // A: [0,64K) B: [64K,128K); 2 buf x 2 half x 16KB
  const int tid = threadIdx.x;
  const int w = tid >> 6, l = tid & 63;
  const int wrow = w >> 2, wcol = w & 3;
  const int row0 = blockIdx.y * 256, col0 = blockIdx.x * 256;
  const int NT = K >> 7;  // K-tiles of 128; requires K%128==0, NT>=2

  i32x8 af[4];
  i32x8 bfr[2];
  f32x4 acc[2][2][4][2] = {};

  auto stage = [&](int mat, int h, int t, int buf) {
    const unsigned char* base = mat ? BT : A;
    const int rbase = (mat ? col0 : row0) + h * 128;
    const int k0 = t * 128;
    char* region = smem + mat * 65536 + buf * 32768 + h * 16384;
#pragma unroll
    for (int j = 0; j < 2; ++j) {
      const int c = j * 512 + w * 64 + l;
      const int r = c >> 3, kc = c & 7;
      const unsigned char* src = base + (size_t)(rbase + r) * K + (k0 + ((kc ^ (r & 7)) << 4));
      __builtin_amdgcn_global_load_lds((const as1_void*)src,
                                       (as3_void*)(region + (j * 512 + w * 64) * 16), 16, 0, 0);
    }
  };
  auto lda = [&](int qa, int buf) {
    const char* region = smem + buf * 32768 + qa * 16384;
#pragma unroll
    for (int i = 0; i < 4; ++i) {
      const int r = wrow * 64 + i * 16 + (l & 15);
      const int kc = (l >> 4) * 2;
      i32x4 lo = *(const i32x4*)(region + r * 128 + ((kc ^ (r & 7)) << 4));
      i32x4 hi = *(const i32x4*)(region + r * 128 + (((kc + 1) ^ (r & 7)) << 4));
      af[i] = __builtin_shufflevector(lo, hi, 0, 1, 2, 3, 4, 5, 6, 7);
    }
  };
  auto ldb = [&](int qb, int buf) {
    const char* region = smem + 65536 + buf * 32768 + qb * 16384;
#pragma unroll
    for (int j = 0; j < 2; ++j) {
      const int r = wcol * 32 + j * 16 + (l & 15);
      const int kc = (l >> 4) * 2;
      i32x4 lo = *(const i32x4*)(region + r * 128 + ((kc ^ (r & 7)) << 4));
      i32x4 hi = *(const i32x4*)(region + r * 128 + (((kc + 1) ^ (r & 7)) << 4));
      bfr[j] = __builtin_shufflevector(lo, hi, 0, 1, 2, 3, 4, 5, 6, 7);
    }
  };
  auto mf = [&](f32x4 (&ac)[4][2]) {
    __builtin_amdgcn_s_setprio(1);
#pragma unroll
    for (int i = 0; i < 4; ++i)
#pragma unroll
      for (int j = 0; j < 2; ++j)
        ac[i][j] = __builtin_amdgcn_mfma_scale_f32_16x16x128_f8f6f4(
            af[i], bfr[j], ac[i][j], 0, 0, 0, 127, 0, 127);
    __builtin_amdgcn_s_setprio(0);
  };
  auto bar = [&]() {
    asm volatile("" ::: "memory");
    __builtin_amdgcn_s_barrier();
    asm volatile("" ::: "memory");
  };

  // prologue: tile 0 -> buf0 (A0,B0,B1,A1); drain A0,B0 -> outstanding [B1x2,A1x2]=4
  stage(0, 0, 0, 0); stage(1, 0, 0, 0); stage(1, 1, 0, 0); stage(0, 1, 0, 0);
  WAITV(4);
  bar();

  for (int t = 0; t < NT - 1; ++t) {
    const int buf = t & 1, nbuf = buf ^ 1;
    // p0: q(0,0); stage A0(t+1)
    lda(0, buf); ldb(0, buf);
    stage(0, 0, t + 1, nbuf);
    WAITV(4);
    bar();
    mf(acc[0][0]);
    // p1: q(0,1); stage B0(t+1)
    ldb(1, buf);
    stage(1, 0, t + 1, nbuf);
    WAITV(4);
    bar();
    mf(acc[0][1]);
    // p2: q(1,1); stage B1(t+1) — no wait
    lda(1, buf);
    stage(1, 1, t + 1, nbuf);
    bar();
    mf(acc[1][1]);
    // p3: q(1,0); re-read B0 frags; stage A1(t+1)
    ldb(0, buf);
    stage(0, 1, t + 1, nbuf);
    WAITV(4);
    bar();
    mf(acc[1][0]);
  }
  {  // last tile (outstanding [B1x2,A1x2])
    const int buf = (NT - 1) & 1;
    lda(0, buf); ldb(0, buf);
    WAITV(2);
    bar();
    mf(acc[0][0]);
    ldb(1, buf);
    WAITV(0);
    bar();
    mf(acc[0][1]);
    lda(1, buf);
    bar();
    mf(acc[1][1]);
    ldb(0, buf);
    bar();
    mf(acc[1][0]);
  }

  // agent-contraction epilogue: hoist qs/bias to registers, DPP butterfly, f32 hid out.
  float qv[2][4][4][2];
  float bp[2][2];
#pragma unroll
  for (int qa = 0; qa < 2; ++qa)
#pragma unroll
    for (int i = 0; i < 4; ++i)
#pragma unroll
      for (int tt = 0; tt < 4; ++tt)
#pragma unroll
        for (int j = 0; j < 2; ++j)
          qv[qa][i][tt][j] =
              qs[(size_t)(row0 + qa * 128 + wrow * 64 + i * 16 + (l >> 4) * 4 + tt) * A_DIM +
                 j * 16 + (l & 15)];
#pragma unroll
  for (int qb = 0; qb < 2; ++qb)
#pragma unroll
    for (int j = 0; j < 2; ++j)
      bp[qb][j] = bias[col0 + qb * 128 + wcol * 32 + j * 16 + (l & 15)];
#pragma unroll
  for (int qa = 0; qa < 2; ++qa)
#pragma unroll
    for (int qb = 0; qb < 2; ++qb) {
      const int e = (col0 >> 5) + qb * 4 + wcol;
#pragma unroll
      for (int i = 0; i < 4; ++i)
#pragma unroll
        for (int tt = 0; tt < 4; ++tt) {
          const int r = row0 + qa * 128 + wrow * 64 + i * 16 + (l >> 4) * 4 + tt;
          float s = 0.0f;
#pragma unroll
          for (int j = 0; j < 2; ++j)
            s = fmaf(qv[qa][i][tt][j], fabsf(acc[qa][qb][i][j][tt] + bp[qb][j]), s);
          s = row16_sum(s);
          if ((l & 15) == 0) hid[(size_t)r * E_DIM + e] = s;
        }
    }
}

// tiny final pass: out[b] = sum_e elu(hid+b1)*wf + sum_e vh*vw2 + vb2
__global__ void final2_kernel(const float* __restrict__ hid, const unsigned short* __restrict__ b1p,
                              const unsigned short* __restrict__ vhp, int ostr,
                              const unsigned short* __restrict__ wf,
                              const float* __restrict__ vw2, const float* __restrict__ vb2,
                              float* __restrict__ out) {
  const int tid = threadIdx.x;  // e
  const int b = blockIdx.x;
  float h = hid[(size_t)b * E_DIM + tid] + bf2f(b1p[(size_t)b * ostr + tid]);
  float hidden = h > 0.0f ? h : (expf(h) - 1.0f);  // elu
  float s = hidden * bf2f(wf[(size_t)b * E_DIM + tid]) +
            bf2f(vhp[(size_t)b * ostr + tid]) * vw2[tid];
  __shared__ float red[4];
#pragma unroll
  for (int o = 32; o > 0; o >>= 1) s += __shfl_down(s, o, 64);
  if ((tid & 63) == 0) red[tid >> 6] = s;
  __syncthreads();
  if (tid == 0) out[b] = red[0] + red[1] + red[2] + red[3] + vb2[0];
}

extern "C" void kernel_launch(void* const* d_in, const int* in_sizes, int n_in,
                              void* d_out, int out_size, void* d_ws, size_t ws_size,
                              hipStream_t stream) {
  const float* agent_qs = (const float*)d_in[0];
  const float* states = (const float*)d_in[1];
  const float* hw1_w1 = (const float*)d_in[2];
  const float* hw1_b1 = (const float*)d_in[3];
  const float* hw1_w2 = (const float*)d_in[4];
  const float* hw1_b2 = (const float*)d_in[5];
  const float* hb1_w = (const float*)d_in[6];
  const float* hb1_b = (const float*)d_in[7];
  const float* hwf_w1 = (const float*)d_in[8];
  const float* hwf_b1 = (const float*)d_in[9];
  const float* hwf_w2 = (const float*)d_in[10];
  const float* hwf_b2 = (const float*)d_in[11];
  const float* v_w1 = (const float*)d_in[12];
  const float* v_b1 = (const float*)d_in[13];
  const float* v_w2 = (const float*)d_in[14];
  const float* v_b2 = (const float*)d_in[15];
  float* out = (float*)d_out;

  size_t off = 0;
  char* ws = (char*)d_ws;
  auto carve = [&](size_t bytes) -> void* {
    void* p = ws + off;
    off = (off + bytes + 255) & ~(size_t)255;
    return p;
  };
  const int NCAT = 2560;  // 1024 h1 | 1024 hf | 256 b1 | 256 vh
  unsigned short* st_bf = (unsigned short*)carve((size_t)B_SZ * S_DIM * 2);
  unsigned short* wcat = (unsigned short*)carve((size_t)NCAT * S_DIM * 2);
  unsigned char* w8T = (unsigned char*)carve((size_t)8192 * H_DIM);
  unsigned short* wf2T = (unsigned short*)carve((size_t)E_DIM * H_DIM * 2);
  float* bcatp = (float*)carve((size_t)NCAT * 4);
  float* bias_p = (float*)carve((size_t)8192 * 4);
  unsigned short* ocat = (unsigned short*)carve((size_t)B_SZ * NCAT * 2);  // cols [0,1024) unused
  unsigned char* a8 = (unsigned char*)carve((size_t)B_SZ * H_DIM);
  unsigned short* wfb = (unsigned short*)carve((size_t)B_SZ * E_DIM * 2);
  float* hid = (float*)carve((size_t)B_SZ * E_DIM * 4);

  // one prep launch: converts/transposes/bias packs (w12 -> permuted fp8 B^T)
  prep_kernel<<<PREP_BLOCKS, 256, 0, stream>>>(
      states, hw1_w1, hwf_w1, hb1_w, v_w1, hw1_w2, hwf_w2, hw1_b1, hwf_b1, hb1_b, v_b1,
      hw1_b2, st_bf, wcat, w8T, wf2T, bcatp, bias_p);

  // consolidated K=512 GEMM: h1 cols -> fp8 a8; hf/b1/vh cols -> bf16 ocat
  gemm_bt<3><<<dim3(NCAT / 128, B_SZ / 128), 256, 0, stream>>>(
      st_bf, S_DIM, wcat, bcatp, ocat, a8, B_SZ, NCAT, S_DIM);

  // w_final = |hf @ hwf_w2 + b|  (A = ocat cols [1024,2048), strided)
  gemm_bt<2><<<dim3(E_DIM / 128, B_SZ / 128), 256, 0, stream>>>(
      ocat + 1024, NCAT, wf2T, hwf_b2, wfb, nullptr, B_SZ, E_DIM, H_DIM);

  // big GEMM in MX-fp8 K=128 with fused |.| + agent contraction -> hid
  gemm256_f8<<<dim3(8192 / 256, B_SZ / 256), 512, 0, stream>>>(
      a8, w8T, bias_p, agent_qs, hid, B_SZ, 8192, H_DIM);

  // tiny epilogue
  final2_kernel<<<B_SZ, 256, 0, stream>>>(hid, ocat + 2048, ocat + 2304, NCAT, wfb, v_w2, v_b2, out);
}

// Round 12
// 150.205 us; speedup vs baseline: 1.9954x; 1.9954x over previous
//
#include <hip/hip_runtime.h>
#include <hip/hip_bf16.h>

#define B_SZ 8192
#define S_DIM 512
#define H_DIM 1024
#define E_DIM 256
#define A_DIM 32

typedef __attribute__((ext_vector_type(4))) float f32x4;
typedef __attribute__((ext_vector_type(8))) __bf16 bf16x8;
typedef __attribute__((ext_vector_type(4))) int i32x4;
typedef __attribute__((ext_vector_type(8))) int i32x8;

using as1_void = __attribute__((address_space(1))) void;
using as3_void = __attribute__((address_space(3))) void;

__device__ __forceinline__ unsigned short f2bfu(float f) {
  unsigned u = __builtin_bit_cast(unsigned, f);
  unsigned r = (u + 0x7FFFu + ((u >> 16) & 1u)) >> 16;
  return (unsigned short)r;
}
__device__ __forceinline__ float bf2f(unsigned short x) {
  unsigned u = ((unsigned)x) << 16;
  return __builtin_bit_cast(float, u);
}
// f32 -> OCP e4m3 via HW packed convert (byte 0)
__device__ __forceinline__ unsigned char f2fp8(float f) {
  return (unsigned char)(__builtin_amdgcn_cvt_pk_fp8_f32(f, f, 0, false) & 0xFF);
}

// 16-lane xor-butterfly sum via DPP (VALU pipe, no LDS traffic).
__device__ __forceinline__ float row16_sum(float s) {
  float t;
  t = __builtin_bit_cast(float, __builtin_amdgcn_update_dpp(
          0, __builtin_bit_cast(int, s), 0xB1, 0xF, 0xF, true));
  s += t;
  t = __builtin_bit_cast(float, __builtin_amdgcn_update_dpp(
          0, __builtin_bit_cast(int, s), 0x4E, 0xF, 0xF, true));
  s += t;
  t = __builtin_bit_cast(float, __builtin_amdgcn_update_dpp(
          0, __builtin_bit_cast(int, s), 0x141, 0xF, 0xF, true));
  s += t;
  t = __builtin_bit_cast(float, __builtin_amdgcn_update_dpp(
          0, __builtin_bit_cast(int, s), 0x140, 0xF, 0xF, true));
  s += t;
  return s;
}

// ---------------- single mega prep kernel ------------------------------------------------
#define PREP_BLOCKS 13866
__global__ void prep_kernel(const float* __restrict__ states, const float* __restrict__ hw1_w1,
                            const float* __restrict__ hwf_w1, const float* __restrict__ hb1_w,
                            const float* __restrict__ v_w1, const float* __restrict__ hw1_w2,
                            const float* __restrict__ hwf_w2, const float* __restrict__ hw1_b1,
                            const float* __restrict__ hwf_b1, const float* __restrict__ hb1_b,
                            const float* __restrict__ v_b1, const float* __restrict__ hw1_b2,
                            unsigned short* __restrict__ st_bf, unsigned short* __restrict__ wcat,
                            unsigned char* __restrict__ w8T, unsigned short* __restrict__ wf2T,
                            float* __restrict__ bcatp, float* __restrict__ bias_p) {
  __shared__ float t[32][33];
  const int tid = threadIdx.x;
  int b = blockIdx.x;
  if (b < 4096) {  // conv
    int idx = b * 1024 + tid * 4;
    const float4 v = *(const float4*)(states + idx);
    ushort4 o;
    o.x = f2bfu(v.x); o.y = f2bfu(v.y); o.z = f2bfu(v.z); o.w = f2bfu(v.w);
    *(ushort4*)(st_bf + idx) = o;
    return;
  }
  b -= 4096;
  if (b >= 9728) {  // bcat / bperm
    b -= 9728;
    if (b < 10) {
      int i = b * 256 + tid;
      if (i < 2560) {
        float v;
        if (i < 1024) v = hw1_b1[i];
        else if (i < 2048) v = hwf_b1[i - 1024];
        else if (i < 2304) v = hb1_b[i - 2048];
        else v = v_b1[i - 2304];
        bcatp[i] = v;
      }
    } else {
      int n = (b - 10) * 256 + tid;
      bias_p[n] = hw1_b2[((n & 31) << 8) + (n >> 5)];
    }
    return;
  }
  // transpose jobs
  const float* src;
  unsigned short* dst;
  int R, C, tile;
  bool perm = false;
  if (b < 512) { src = hw1_w1; dst = wcat; R = 512; C = 1024; tile = b; }
  else if (b < 1024) { src = hwf_w1; dst = wcat + (size_t)1024 * 512; R = 512; C = 1024; tile = b - 512; }
  else if (b < 1152) { src = hb1_w; dst = wcat + (size_t)2048 * 512; R = 512; C = 256; tile = b - 1024; }
  else if (b < 1280) { src = v_w1; dst = wcat + (size_t)2304 * 512; R = 512; C = 256; tile = b - 1152; }
  else if (b < 9472) { src = hw1_w2; dst = nullptr; R = 1024; C = 8192; tile = b - 1280; perm = true; }
  else { src = hwf_w2; dst = wf2T; R = 1024; C = 256; tile = b - 9472; }
  const int tpc = C >> 5;
  const int c0 = (tile % tpc) * 32, r0 = (tile / tpc) * 32;
  const int tx = tid & 31, ty = tid >> 5;
#pragma unroll
  for (int i = 0; i < 4; ++i) {
    int r = r0 + ty + i * 8;
    t[ty + i * 8][tx] = src[(size_t)r * C + c0 + tx];
  }
  __syncthreads();
#pragma unroll
  for (int i = 0; i < 4; ++i) {
    int c = c0 + ty + i * 8;
    if (perm) {
      size_t co = (size_t)(((c & 255) << 5) + (c >> 8));
      w8T[co * 1024 + r0 + tx] = f2fp8(t[tx][ty + i * 8]);
    } else {
      dst[(size_t)c * R + r0 + tx] = f2bfu(t[tx][ty + i * 8]);
    }
  }
}

// ---------------- 128x128 2-phase GEMM (m97 structure) -----------------------------------
// ACT==2: abs -> bf16. ACT==3 (S-GEMM): relu except cols [2048,2304); cols<1024 -> fp8 a8,
// else bf16 Cp.
template <int ACT>
__global__ void gemm_bt(const unsigned short* __restrict__ A, int Astr,
                        const unsigned short* __restrict__ BT,
                        const float* __restrict__ bias, void* __restrict__ Cp,
                        unsigned char* __restrict__ a8, int M, int N, int K) {
  __shared__ unsigned short As[128 * 64];
  __shared__ unsigned short Bs[128 * 64];
  const int tid = threadIdx.x;
  const int w = tid >> 6, l = tid & 63;
  const int wr = w >> 1, wc = w & 1;
  const int row0 = blockIdx.y * 128, col0 = blockIdx.x * 128;
  f32x4 acc[4][4] = {};
  for (int k0 = 0; k0 < K; k0 += 64) {
    __syncthreads();
#pragma unroll
    for (int i = 0; i < 4; ++i) {
      int cbase = i * 256 + w * 64;
      int c = cbase + l;
      int r = c >> 3, kc = c & 7;
      const unsigned short* src = A + (size_t)(row0 + r) * Astr + (k0 + kc * 8);
      __builtin_amdgcn_global_load_lds((const as1_void*)src, (as3_void*)&As[cbase * 8], 16, 0, 0);
    }
#pragma unroll
    for (int i = 0; i < 4; ++i) {
      int cbase = i * 256 + w * 64;
      int c = cbase + l;
      int r = c >> 3, kc = c & 7;
      const unsigned short* src = BT + (size_t)(col0 + r) * K + (k0 + kc * 8);
      __builtin_amdgcn_global_load_lds((const as1_void*)src, (as3_void*)&Bs[cbase * 8], 16, 0, 0);
    }
    __syncthreads();
#pragma unroll
    for (int kk = 0; kk < 2; ++kk) {
      bf16x8 af[4], bfr[4];
#pragma unroll
      for (int i = 0; i < 4; ++i)
        af[i] = *(const bf16x8*)&As[(wr * 64 + i * 16 + (l & 15)) * 64 + kk * 32 + (l >> 4) * 8];
#pragma unroll
      for (int j = 0; j < 4; ++j)
        bfr[j] = *(const bf16x8*)&Bs[(wc * 64 + j * 16 + (l & 15)) * 64 + kk * 32 + (l >> 4) * 8];
#pragma unroll
      for (int i = 0; i < 4; ++i)
#pragma unroll
        for (int j = 0; j < 4; ++j)
          acc[i][j] = __builtin_amdgcn_mfma_f32_16x16x32_bf16(af[i], bfr[j], acc[i][j], 0, 0, 0);
    }
  }
#pragma unroll
  for (int i = 0; i < 4; ++i)
#pragma unroll
    for (int j = 0; j < 4; ++j)
#pragma unroll
      for (int t = 0; t < 4; ++t) {
        int r = row0 + wr * 64 + i * 16 + (l >> 4) * 4 + t;
        int c = col0 + wc * 64 + j * 16 + (l & 15);
        float v = acc[i][j][t] + bias[c];
        if (ACT == 2) {
          v = fabsf(v);
          ((unsigned short*)Cp)[(size_t)r * N + c] = f2bfu(v);
        } else {  // ACT == 3
          if (!(c >= 2048 && c < 2304)) v = fmaxf(v, 0.0f);
          if (c < 1024)
            a8[(size_t)r * 1024 + c] = f2fp8(v);
          else
            ((unsigned short*)Cp)[(size_t)r * N + c] = f2bfu(v);
        }
      }
}

// ---------------- 128x128 MX-fp8 K=128 GEMM (m148 recipe) + fused agent contraction ------
// m97 2-barrier structure, BK=128 (one scaled MFMA per (i,j) per K-step), 256 threads,
// 32 KB LDS -> ~3 blocks/CU cross-block overlap. Register demand ~180 (acc 64 + frags 64)
// — no spill (r10/r11's 256-tile fp8 blew the 256/wave budget and spilled 275 MB).
// Epilogue (cols permuted n'=e*32+a): e = (col0>>5)+wc*2+(j>>1), a = ((j&1)<<4)+(l&15);
// sum j-pair then 16-lane DPP butterfly; lane (l&15)==0 writes hid[r][e] f32.
__global__ __launch_bounds__(256, 2) void gemm128_f8(
    const unsigned char* __restrict__ A, const unsigned char* __restrict__ BT,
    const float* __restrict__ bias, const float* __restrict__ qs,
    float* __restrict__ hid, int M, int N, int K) {
  __shared__ __align__(16) unsigned char As[128 * 128];
  __shared__ __align__(16) unsigned char Bs[128 * 128];
  const int tid = threadIdx.x;
  const int w = tid >> 6, l = tid & 63;
  const int wr = w >> 1, wc = w & 1;
  const int row0 = blockIdx.y * 128, col0 = blockIdx.x * 128;
  f32x4 acc[4][4] = {};
  for (int k0 = 0; k0 < K; k0 += 128) {
    __syncthreads();
#pragma unroll
    for (int i = 0; i < 4; ++i) {
      int cbase = i * 256 + w * 64;
      int c = cbase + l;
      int r = c >> 3, kc = c & 7;  // 8 x 16B chunks per 128-fp8 row
      const unsigned char* src = A + (size_t)(row0 + r) * K + (k0 + ((kc ^ (r & 7)) << 4));
      __builtin_amdgcn_global_load_lds((const as1_void*)src, (as3_void*)&As[cbase * 16], 16, 0, 0);
    }
#pragma unroll
    for (int i = 0; i < 4; ++i) {
      int cbase = i * 256 + w * 64;
      int c = cbase + l;
      int r = c >> 3, kc = c & 7;
      const unsigned char* src = BT + (size_t)(col0 + r) * K + (k0 + ((kc ^ (r & 7)) << 4));
      __builtin_amdgcn_global_load_lds((const as1_void*)src, (as3_void*)&Bs[cbase * 16], 16, 0, 0);
    }
    __syncthreads();
    i32x8 af[4], bfr[4];
#pragma unroll
    for (int i = 0; i < 4; ++i) {
      const int r = wr * 64 + i * 16 + (l & 15);
      const int kc = (l >> 4) * 2;
      i32x4 lo = *(const i32x4*)&As[r * 128 + ((kc ^ (r & 7)) << 4)];
      i32x4 hi = *(const i32x4*)&As[r * 128 + (((kc + 1) ^ (r & 7)) << 4)];
      af[i] = __builtin_shufflevector(lo, hi, 0, 1, 2, 3, 4, 5, 6, 7);
    }
#pragma unroll
    for (int j = 0; j < 4; ++j) {
      const int r = wc * 64 + j * 16 + (l & 15);
      const int kc = (l >> 4) * 2;
      i32x4 lo = *(const i32x4*)&Bs[r * 128 + ((kc ^ (r & 7)) << 4)];
      i32x4 hi = *(const i32x4*)&Bs[r * 128 + (((kc + 1) ^ (r & 7)) << 4)];
      bfr[j] = __builtin_shufflevector(lo, hi, 0, 1, 2, 3, 4, 5, 6, 7);
    }
    __builtin_amdgcn_s_setprio(1);
#pragma unroll
    for (int i = 0; i < 4; ++i)
#pragma unroll
      for (int j = 0; j < 4; ++j)
        acc[i][j] = __builtin_amdgcn_mfma_scale_f32_16x16x128_f8f6f4(
            af[i], bfr[j], acc[i][j], 0, 0, 0, 127, 0, 127);
    __builtin_amdgcn_s_setprio(0);
  }

  // agent-contraction epilogue: hoist qs/bias to registers, j-pair sum + DPP butterfly.
  float qv[4][4][2];  // [i][tt][a-half] for this wave's 16 rows
  float bp[4];
#pragma unroll
  for (int i = 0; i < 4; ++i)
#pragma unroll
    for (int tt = 0; tt < 4; ++tt) {
      const int r = row0 + wr * 64 + i * 16 + (l >> 4) * 4 + tt;
      qv[i][tt][0] = qs[(size_t)r * A_DIM + (l & 15)];
      qv[i][tt][1] = qs[(size_t)r * A_DIM + 16 + (l & 15)];
    }
#pragma unroll
  for (int j = 0; j < 4; ++j)
    bp[j] = bias[col0 + wc * 64 + j * 16 + (l & 15)];
#pragma unroll
  for (int i = 0; i < 4; ++i)
#pragma unroll
    for (int e2 = 0; e2 < 2; ++e2) {
      const int e = (col0 >> 5) + wc * 2 + e2;
#pragma unroll
      for (int tt = 0; tt < 4; ++tt) {
        const int r = row0 + wr * 64 + i * 16 + (l >> 4) * 4 + tt;
        float s = fmaf(qv[i][tt][0], fabsf(acc[i][e2 * 2][tt] + bp[e2 * 2]), 0.0f);
        s = fmaf(qv[i][tt][1], fabsf(acc[i][e2 * 2 + 1][tt] + bp[e2 * 2 + 1]), s);
        s = row16_sum(s);
        if ((l & 15) == 0) hid[(size_t)r * E_DIM + e] = s;
      }
    }
}

// tiny final pass: out[b] = sum_e elu(hid+b1)*wf + sum_e vh*vw2 + vb2
__global__ void final2_kernel(const float* __restrict__ hid, const unsigned short* __restrict__ b1p,
                              const unsigned short* __restrict__ vhp, int ostr,
                              const unsigned short* __restrict__ wf,
                              const float* __restrict__ vw2, const float* __restrict__ vb2,
                              float* __restrict__ out) {
  const int tid = threadIdx.x;  // e
  const int b = blockIdx.x;
  float h = hid[(size_t)b * E_DIM + tid] + bf2f(b1p[(size_t)b * ostr + tid]);
  float hidden = h > 0.0f ? h : (expf(h) - 1.0f);  // elu
  float s = hidden * bf2f(wf[(size_t)b * E_DIM + tid]) +
            bf2f(vhp[(size_t)b * ostr + tid]) * vw2[tid];
  __shared__ float red[4];
#pragma unroll
  for (int o = 32; o > 0; o >>= 1) s += __shfl_down(s, o, 64);
  if ((tid & 63) == 0) red[tid >> 6] = s;
  __syncthreads();
  if (tid == 0) out[b] = red[0] + red[1] + red[2] + red[3] + vb2[0];
}

extern "C" void kernel_launch(void* const* d_in, const int* in_sizes, int n_in,
                              void* d_out, int out_size, void* d_ws, size_t ws_size,
                              hipStream_t stream) {
  const float* agent_qs = (const float*)d_in[0];
  const float* states = (const float*)d_in[1];
  const float* hw1_w1 = (const float*)d_in[2];
  const float* hw1_b1 = (const float*)d_in[3];
  const float* hw1_w2 = (const float*)d_in[4];
  const float* hw1_b2 = (const float*)d_in[5];
  const float* hb1_w = (const float*)d_in[6];
  const float* hb1_b = (const float*)d_in[7];
  const float* hwf_w1 = (const float*)d_in[8];
  const float* hwf_b1 = (const float*)d_in[9];
  const float* hwf_w2 = (const float*)d_in[10];
  const float* hwf_b2 = (const float*)d_in[11];
  const float* v_w1 = (const float*)d_in[12];
  const float* v_b1 = (const float*)d_in[13];
  const float* v_w2 = (const float*)d_in[14];
  const float* v_b2 = (const float*)d_in[15];
  float* out = (float*)d_out;

  size_t off = 0;
  char* ws = (char*)d_ws;
  auto carve = [&](size_t bytes) -> void* {
    void* p = ws + off;
    off = (off + bytes + 255) & ~(size_t)255;
    return p;
  };
  const int NCAT = 2560;  // 1024 h1 | 1024 hf | 256 b1 | 256 vh
  unsigned short* st_bf = (unsigned short*)carve((size_t)B_SZ * S_DIM * 2);
  unsigned short* wcat = (unsigned short*)carve((size_t)NCAT * S_DIM * 2);
  unsigned char* w8T = (unsigned char*)carve((size_t)8192 * H_DIM);
  unsigned short* wf2T = (unsigned short*)carve((size_t)E_DIM * H_DIM * 2);
  float* bcatp = (float*)carve((size_t)NCAT * 4);
  float* bias_p = (float*)carve((size_t)8192 * 4);
  unsigned short* ocat = (unsigned short*)carve((size_t)B_SZ * NCAT * 2);  // cols [0,1024) unused
  unsigned char* a8 = (unsigned char*)carve((size_t)B_SZ * H_DIM);
  unsigned short* wfb = (unsigned short*)carve((size_t)B_SZ * E_DIM * 2);
  float* hid = (float*)carve((size_t)B_SZ * E_DIM * 4);

  // one prep launch: converts/transposes/bias packs (w12 -> permuted fp8 B^T)
  prep_kernel<<<PREP_BLOCKS, 256, 0, stream>>>(
      states, hw1_w1, hwf_w1, hb1_w, v_w1, hw1_w2, hwf_w2, hw1_b1, hwf_b1, hb1_b, v_b1,
      hw1_b2, st_bf, wcat, w8T, wf2T, bcatp, bias_p);

  // consolidated K=512 GEMM: h1 cols -> fp8 a8; hf/b1/vh cols -> bf16 ocat
  gemm_bt<3><<<dim3(NCAT / 128, B_SZ / 128), 256, 0, stream>>>(
      st_bf, S_DIM, wcat, bcatp, ocat, a8, B_SZ, NCAT, S_DIM);

  // w_final = |hf @ hwf_w2 + b|  (A = ocat cols [1024,2048), strided)
  gemm_bt<2><<<dim3(E_DIM / 128, B_SZ / 128), 256, 0, stream>>>(
      ocat + 1024, NCAT, wf2T, hwf_b2, wfb, nullptr, B_SZ, E_DIM, H_DIM);

  // big GEMM in MX-fp8 K=128 (128-tile m148 recipe) with fused |.| + agent contraction
  gemm128_f8<<<dim3(8192 / 128, B_SZ / 128), 256, 0, stream>>>(
      a8, w8T, bias_p, agent_qs, hid, B_SZ, 8192, H_DIM);

  // tiny epilogue
  final2_kernel<<<B_SZ, 256, 0, stream>>>(hid, ocat + 2048, ocat + 2304, NCAT, wfb, v_w2, v_b2, out);
}